// Round 14
// baseline (179.479 us; speedup 1.0000x reference)
//
#include <hip/hip_runtime.h>
#include <hip/hip_bf16.h>
#include <stdint.h>

// ---------------------------------------------------------------------------
// MHA forward, bf16 MFMA path (gfx950).  B=1, S=4096, D=1024, H=16, HD=64.
//   1. preprocess: R13 vectorized version (frozen).
//   2. gemm_qkv ROUND-23: 2-phase prefetch. Old loop = barrier->stage->
//      barrier(drain)->compute exposed the full staging latency每 step
//      (MfmaUtil 20%, 560 TF). New loop: double-buffered LDS (2x16KB),
//      issue next tile's global_load_lds BEFORE computing current, ONE
//      __syncthreads per step (its implicit vmcnt(0) drain retires the
//      prefetch that ran UNDER the 16 MFMA + 8 ds_read). Hazards: buf
//      written at step t first read after step-t barrier; buf reused at
//      t+2 protected by each wave's lgkm drain at its own barrier.
//      Bit-identical math. Q pre-scaled 0.125*log2e; K,V fragment-packed.
//   3. flash_attn: R7 kernel FROZEN (46.2 us best; 6 geometries tried).
//   4. gemm_out: same 2-phase treatment of the 128x128 acc[4][4] version.
//   Ledger: R7 178.2 | R10 183.4 (BK64 A/B) | R12 184.3 | R13 176.7.
//   Non-flash invariant ~130 us across 4 pre/out variants -> pre/out are
//   latency/overhead-bound, not throughput-bound; only gemm_qkv's loop
//   structure remains as a measured-precedent lever (T3 minimum 2-phase).
// ---------------------------------------------------------------------------

typedef __bf16 bf16;
typedef __bf16 bf16x2_t __attribute__((ext_vector_type(2)));
typedef __bf16 bf16x4 __attribute__((ext_vector_type(4)));
typedef __bf16 bf16x8 __attribute__((ext_vector_type(8)));
typedef float  f32x4  __attribute__((ext_vector_type(4)));

#define MFMA32(a, b, c) __builtin_amdgcn_mfma_f32_16x16x32_bf16((a), (b), (c), 0, 0, 0)

static constexpr int S_LEN  = 4096;
static constexpr int DMODEL = 1024;
static constexpr int HDIM   = 64;

#define GLOAD_LDS16(g, l)                                                      \
  __builtin_amdgcn_global_load_lds((__attribute__((address_space(1))) void*)(g), \
                                   (__attribute__((address_space(3))) void*)(l), 16, 0, 0)

// ------------- fused preprocess: cast x + 4 weight transposes --------------
__global__ __launch_bounds__(256) void preprocess(const float* __restrict__ x,
                                                  const float* __restrict__ Wq,
                                                  const float* __restrict__ Wk,
                                                  const float* __restrict__ Wv,
                                                  const float* __restrict__ Wo,
                                                  bf16* __restrict__ xb,
                                                  bf16* __restrict__ Wt,
                                                  bf16* __restrict__ Wot) {
  __shared__ float tile[64][65];
  const int t = threadIdx.x, b = blockIdx.x;
  if (b < 1024) {
#pragma unroll
    for (int i = 0; i < 4; i++) {
      int idx = b * 1024 + i * 256 + t;
      float4 v = ((const float4*)x)[idx];
      bf16x4 o;
      o[0] = (bf16)v.x; o[1] = (bf16)v.y; o[2] = (bf16)v.z; o[3] = (bf16)v.w;
      ((bf16x4*)xb)[idx] = o;
    }
    return;
  }
  const int id = b - 1024;
  const int wsel = id >> 8;
  const int t2 = id & 255;
  const int kb = (t2 & 15) * 64, nb = (t2 >> 4) * 64;
  const float* src = (wsel == 0) ? Wq : (wsel == 1) ? Wk : (wsel == 2) ? Wv : Wo;
  bf16* dst = (wsel < 3) ? (Wt + (size_t)wsel * 1024 * 1024) : Wot;
  // read: 4 iters of float4 (1KB/wave), LDS banks 2-way (free)
#pragma unroll
  for (int i = 0; i < 4; i++) {
    int idx = t + i * 256;                 // 0..1023
    int r = idx >> 4, c4 = (idx & 15) * 4;
    float4 v = *(const float4*)&src[(size_t)(kb + r) * 1024 + nb + c4];
    tile[r][c4] = v.x; tile[r][c4 + 1] = v.y;
    tile[r][c4 + 2] = v.z; tile[r][c4 + 3] = v.w;
  }
  __syncthreads();
  // write: 4 iters of bf16x4 along the contiguous (kb+rr) direction
#pragma unroll
  for (int i = 0; i < 4; i++) {
    int idx = t + i * 256;
    int cc = idx >> 4, rr4 = (idx & 15) * 4;
    bf16x4 o;
    o[0] = (bf16)tile[rr4][cc];     o[1] = (bf16)tile[rr4 + 1][cc];
    o[2] = (bf16)tile[rr4 + 2][cc]; o[3] = (bf16)tile[rr4 + 3][cc];
    *(bf16x4*)&dst[(size_t)(nb + cc) * 1024 + kb + rr4] = o;
  }
}

// ------------- gemm_qkv: 128x128 tile, K=1024, BK=32, 2-phase --------------
// Outputs:
//   n0 <  1024 : Qb[row][col] = acc * 0.18033688 (0.125*log2e), stride 1024
//   n0 <  2048 : Kf packed (R16 layout)
//   else       : Vf packed (R16 layout)
__global__ __launch_bounds__(256) void gemm_qkv(const bf16* __restrict__ A,
                                                const bf16* __restrict__ Bt,
                                                bf16* __restrict__ Qb,
                                                bf16* __restrict__ Kf,
                                                bf16* __restrict__ Vf) {
  __shared__ bf16 lsA[2][128 * 32];
  __shared__ bf16 lsB[2][128 * 32];
  const int tid = threadIdx.x, w = tid >> 6, lane = tid & 63;
  const int l15 = lane & 15, quad = lane >> 4;
  const int m0 = blockIdx.x * 128, n0 = blockIdx.y * 128;
  const int wm = (w >> 1) * 64, wn = (w & 1) * 64;
  const int rowA = lane >> 2;
  const int colk = (((lane & 3) ^ ((lane >> 3) & 3))) * 8;  // inverse-swizzled src
  const int rsl = (l15 >> 1) & 3;                           // read-side swizzle

  f32x4 acc[4][4] = {};

  auto stage = [&](int buf, int k0) {
#pragma unroll
    for (int i = 0; i < 2; i++) {
      int s = w * 2 + i;
      const bf16* ga = A + (size_t)(m0 + s * 16 + rowA) * 1024 + k0 + colk;
      GLOAD_LDS16(ga, lsA[buf] + s * 512);
      const bf16* gb = Bt + (size_t)(n0 + s * 16 + rowA) * 1024 + k0 + colk;
      GLOAD_LDS16(gb, lsB[buf] + s * 512);
    }
  };

  stage(0, 0);
  __syncthreads();                         // implicit vmcnt(0): buf0 ready
  int cur = 0;
  for (int k0 = 0; k0 < 1024; k0 += 32) {
    if (k0 + 32 < 1024) stage(cur ^ 1, k0 + 32);   // prefetch under compute

    bf16x8 af[4], bfr[4];
#pragma unroll
    for (int r = 0; r < 4; r++)
      af[r] = *(const bf16x8*)(lsA[cur] + (wm + r * 16 + l15) * 32 + (quad ^ rsl) * 8);
#pragma unroll
    for (int c = 0; c < 4; c++)
      bfr[c] = *(const bf16x8*)(lsB[cur] + (wn + c * 16 + l15) * 32 + (quad ^ rsl) * 8);
#pragma unroll
    for (int r = 0; r < 4; r++)
#pragma unroll
      for (int c = 0; c < 4; c++)
        acc[r][c] = MFMA32(af[r], bfr[c], acc[r][c]);

    __syncthreads();                       // drains vmcnt (next buf staged)
    cur ^= 1;                              // + lgkm (my reads done) for all
  }

  if (n0 < 1024) {
    // ---- Q ----
#pragma unroll
    for (int r = 0; r < 4; r++) {
#pragma unroll
      for (int c = 0; c < 4; c++) {
        int col = n0 + wn + c * 16 + l15;
#pragma unroll
        for (int e = 0; e < 4; e++) {
          int row = m0 + wm + r * 16 + quad * 4 + e;
          Qb[(size_t)row * 1024 + col] = (bf16)(acc[r][c][e] * 0.18033688f);
        }
      }
    }
  } else if (n0 < 2048) {
    // ---- K packed ----
    const int h  = (n0 - 1024 + wn) >> 6;
    const int g0 = (m0 + wm) >> 5;
    bf16* base = Kf + (size_t)(h * 128 + g0) * 2048 +
                 (quad & 1) * 1024 + (l15 >> 3) * 128 + (quad >> 1) * 32 + (l15 & 7);
#pragma unroll
    for (int r = 0; r < 4; r++) {
#pragma unroll
      for (int c = 0; c < 4; c++) {
#pragma unroll
        for (int e = 0; e < 4; e++) {
          base[(r >> 1) * 2048 + (r & 1) * 64 + (c >> 1) * 512 + (c & 1) * 256 + e * 8] =
              (bf16)acc[r][c][e];
        }
      }
    }
  } else {
    // ---- V packed ----
    const int h  = (n0 - 2048 + wn) >> 6;
    const int g0 = (m0 + wm) >> 5;
    bf16* base = Vf + (size_t)(h * 128 + g0) * 2048 +
                 (quad >> 1) * 128 + l15 * 8 + (quad & 1) * 4;
#pragma unroll
    for (int r = 0; r < 4; r++) {
#pragma unroll
      for (int c = 0; c < 4; c++) {
        bf16x4 pk;
#pragma unroll
        for (int e = 0; e < 4; e++) pk[e] = (bf16)acc[r][c][e];
        *(bf16x4*)(base + (r >> 1) * 2048 + (r & 1) * 256 + c * 512) = pk;
      }
    }
  }
}

// ----------------------------- flash attention -----------------------------
// R7 kernel FROZEN (measured 46.2-48.9 us). 1024 blocks, one 64-q tile each,
// 4 key-split waves, K+V register ping-pong, permuted S^T packing, chunked
// reduction. K/V loads from fragment-packed Kf/Vf: dense 1KB wave-reads.
__global__ __launch_bounds__(256, 2) void flash_attn(const bf16* __restrict__ Qb,
                                                     const bf16* __restrict__ Kf,
                                                     const bf16* __restrict__ Vf,
                                                     bf16* __restrict__ Ctx) {
  __shared__ float Obuf[4][16][68];   // 17.4 KB: per-wave partial O, one qg chunk
  __shared__ float Lbuf[4][4][64];    // 4 KB
  const int tid = threadIdx.x, w = tid >> 6, lane = tid & 63;
  const int l15 = lane & 15, quad = lane >> 4;
  const int i = blockIdx.x;
  const int head = (i & 7) + 8 * ((i >> 3) & 1);
  const int qt_raw = i >> 4;
  const int qb = (qt_raw < 32) ? qt_raw : (95 - qt_raw);
  const int hq = head * HDIM;

  const int T = (qb >> 1) + 1;              // 128-key tiles

  // Packed per-wave base pointers: group g = j*4 + w.
  const bf16* Kw = Kf + (size_t)(head * 128 + w) * 2048 + lane * 8;
  const bf16* Vw = Vf + (size_t)(head * 128 + w) * 2048 + lane * 8;

  // Q frags (B-operand): q = qb*64 + qg*16 + l15, d = kk*32 + quad*8 + j
  bf16x8 qf[4][2];
#pragma unroll
  for (int qg = 0; qg < 4; qg++)
#pragma unroll
    for (int kk = 0; kk < 2; kk++)
      qf[qg][kk] = *(const bf16x8*)(Qb + (size_t)(qb * 64 + qg * 16 + l15) * 1024 +
                                    hq + kk * 32 + quad * 8);

  f32x4 oacc[4][4] = {};
  float lsum[4] = {0.f, 0.f, 0.f, 0.f};

  auto load_k = [&](int j, bf16x8 (&kf)[2][2]) {
#pragma unroll
    for (int c = 0; c < 2; c++)
#pragma unroll
      for (int kk = 0; kk < 2; kk++)
        kf[c][kk] = *(const bf16x8*)(Kw + j * 8192 + c * 1024 + kk * 512);
  };
  auto load_v = [&](int j, bf16x8 (&vf)[4]) {
#pragma unroll
    for (int dg = 0; dg < 4; dg++)
      vf[dg] = *(const bf16x8*)(Vw + j * 8192 + dg * 512);
  };
  auto compute = [&](int j, bf16x8 (&kf)[2][2], bf16x8 (&vf)[4]) {
    // S^T = K Q^T : C row = key-slot quad*4+e (matrix c), col = q = l15
    f32x4 sacc[2][4] = {};
    __builtin_amdgcn_s_setprio(1);
#pragma unroll
    for (int kk = 0; kk < 2; kk++)
#pragma unroll
      for (int c = 0; c < 2; c++)
#pragma unroll
        for (int qg = 0; qg < 4; qg++)
          sacc[c][qg] = MFMA32(kf[c][kk], qf[qg][kk], sacc[c][qg]);
    __builtin_amdgcn_s_setprio(0);

    bf16x8 pfr[4];
    if (j == T - 1) {
      const int kb0 = j * 128 + w * 32 + quad * 8;   // + 4c + e = actual key
#pragma unroll
      for (int qg = 0; qg < 4; qg++) {
        const int qrow = qb * 64 + qg * 16 + l15;
        bf16x8 pb;
#pragma unroll
        for (int c = 0; c < 2; c++)
#pragma unroll
          for (int e = 0; e < 4; e++) {
            float s = sacc[c][qg][e];
            if (kb0 + 4 * c + e > qrow) s = -1e30f;
            float pv = __builtin_amdgcn_exp2f(s);
            lsum[qg] += pv;
            pb[c * 4 + e] = (bf16)pv;
          }
        pfr[qg] = pb;
      }
    } else {
#pragma unroll
      for (int qg = 0; qg < 4; qg++) {
        bf16x8 pb;
#pragma unroll
        for (int c = 0; c < 2; c++)
#pragma unroll
          for (int e = 0; e < 4; e++) {
            float pv = __builtin_amdgcn_exp2f(sacc[c][qg][e]);
            lsum[qg] += pv;
            pb[c * 4 + e] = (bf16)pv;
          }
        pfr[qg] = pb;
      }
    }

    // O += P V  (K=32, P direct from registers)
    __builtin_amdgcn_s_setprio(1);
#pragma unroll
    for (int qg = 0; qg < 4; qg++)
#pragma unroll
      for (int dg = 0; dg < 4; dg++)
        oacc[qg][dg] = MFMA32(pfr[qg], vf[dg], oacc[qg][dg]);
    __builtin_amdgcn_s_setprio(0);
  };

  bf16x8 kfA[2][2], vfA[4], kfB[2][2], vfB[4];
  load_k(0, kfA); load_v(0, vfA);
  for (int j = 0; j < T; j += 2) {
    if (j + 1 < T) { load_k(j + 1, kfB); load_v(j + 1, vfB); }
    compute(j, kfA, vfA);
    if (j + 2 < T) { load_k(j + 2, kfA); load_v(j + 2, vfA); }
    if (j + 1 < T) compute(j + 1, kfB, vfB);
  }

  // ---- chunked cross-wave reduction: one qg (16 q-rows) at a time ----
#pragma unroll
  for (int qg = 0; qg < 4; qg++)
    Lbuf[w][quad][qg * 16 + l15] = lsum[qg];

  const int row = tid >> 4;               // 0..15 (local q within chunk)
  const int col = (tid & 15) * 4;         // 0..60 (d within head)
  for (int qg = 0; qg < 4; qg++) {
#pragma unroll
    for (int dg = 0; dg < 4; dg++)
#pragma unroll
      for (int e = 0; e < 4; e++)
        Obuf[w][quad * 4 + e][dg * 16 + l15] = oacc[qg][dg][e];
    __syncthreads();                      // writes visible
    f32x4 os = {};
#pragma unroll
    for (int ww = 0; ww < 4; ww++)
      os += *(const f32x4*)&Obuf[ww][row][col];
    float lr = 0.f;
#pragma unroll
    for (int ww = 0; ww < 4; ww++)
#pragma unroll
      for (int qq = 0; qq < 4; qq++)
        lr += Lbuf[ww][qq][qg * 16 + row];
    const float linv = 1.f / lr;
    bf16x4 ob;
#pragma unroll
    for (int e2 = 0; e2 < 4; e2++) ob[e2] = (bf16)(os[e2] * linv);
    *(bf16x4*)(Ctx + (size_t)(qb * 64 + qg * 16 + row) * DMODEL + hq + col) = ob;
    __syncthreads();                      // reads done before next chunk
  }
}

// ------------- gemm_out: 128x128 tile, K=1024, BK=32, 2-phase --------------
__global__ __launch_bounds__(256) void gemm_out(const bf16* __restrict__ A,
                                                const bf16* __restrict__ Bt,
                                                float* __restrict__ C,
                                                const float* __restrict__ bias) {
  __shared__ bf16 lsA[2][128 * 32];
  __shared__ bf16 lsB[2][128 * 32];
  const int tid = threadIdx.x, w = tid >> 6, lane = tid & 63;
  const int l15 = lane & 15, quad = lane >> 4;
  const int m0 = blockIdx.x * 128, n0 = blockIdx.y * 128;
  const int wm = (w >> 1) * 64, wn = (w & 1) * 64;
  const int rowA = lane >> 2;
  const int colk = (((lane & 3) ^ ((lane >> 3) & 3))) * 8;  // inverse-swizzled src
  const int rsl = (l15 >> 1) & 3;                           // read-side swizzle

  f32x4 acc[4][4] = {};

  auto stage = [&](int buf, int k0) {
#pragma unroll
    for (int i = 0; i < 2; i++) {
      int s = w * 2 + i;
      const bf16* ga = A + (size_t)(m0 + s * 16 + rowA) * 1024 + k0 + colk;
      GLOAD_LDS16(ga, lsA[buf] + s * 512);
      const bf16* gb = Bt + (size_t)(n0 + s * 16 + rowA) * 1024 + k0 + colk;
      GLOAD_LDS16(gb, lsB[buf] + s * 512);
    }
  };

  stage(0, 0);
  __syncthreads();
  int cur = 0;
  for (int k0 = 0; k0 < 1024; k0 += 32) {
    if (k0 + 32 < 1024) stage(cur ^ 1, k0 + 32);

    bf16x8 af[4], bfr[4];
#pragma unroll
    for (int r = 0; r < 4; r++)
      af[r] = *(const bf16x8*)(lsA[cur] + (wm + r * 16 + l15) * 32 + (quad ^ rsl) * 8);
#pragma unroll
    for (int c = 0; c < 4; c++)
      bfr[c] = *(const bf16x8*)(lsB[cur] + (wn + c * 16 + l15) * 32 + (quad ^ rsl) * 8);
#pragma unroll
    for (int r = 0; r < 4; r++)
#pragma unroll
      for (int c = 0; c < 4; c++)
        acc[r][c] = MFMA32(af[r], bfr[c], acc[r][c]);

    __syncthreads();
    cur ^= 1;
  }

#pragma unroll
  for (int r = 0; r < 4; r++) {
#pragma unroll
    for (int c = 0; c < 4; c++) {
      int col = n0 + wn + c * 16 + l15;
      float bv = bias[col];
#pragma unroll
      for (int e = 0; e < 4; e++) {
        int row = m0 + wm + r * 16 + quad * 4 + e;
        C[(size_t)row * 1024 + col] = acc[r][c][e] + bv;
      }
    }
  }
}

// ------------------------------- launcher ----------------------------------
extern "C" void kernel_launch(void* const* d_in, const int* in_sizes, int n_in,
                              void* d_out, int out_size, void* d_ws, size_t ws_size,
                              hipStream_t stream) {
  const float* x  = (const float*)d_in[0];
  const float* Wq = (const float*)d_in[1];
  const float* Wk = (const float*)d_in[2];
  const float* Wv = (const float*)d_in[3];
  const float* Wo = (const float*)d_in[4];
  const float* bo = (const float*)d_in[5];

  char* ws = (char*)d_ws;                    // 48 MB total
  bf16* xb  = (bf16*)(ws);                   // 8 MB  [4096][1024]
  bf16* Wt  = (bf16*)(ws + (8u  << 20));     // 6 MB  [3072][1024]
  bf16* Wot = (bf16*)(ws + (14u << 20));     // 2 MB  [1024][1024]
  bf16* Qb  = (bf16*)(ws + (16u << 20));     // 8 MB  [4096][1024]
  bf16* Kf  = (bf16*)(ws + (24u << 20));     // 8 MB  packed K frags
  bf16* Vf  = (bf16*)(ws + (32u << 20));     // 8 MB  packed V frags
  bf16* Ctx = (bf16*)(ws + (40u << 20));     // 8 MB  [4096][1024]

  preprocess<<<2048, 256, 0, stream>>>(x, Wq, Wk, Wv, Wo, xb, Wt, Wot);
  gemm_qkv<<<dim3(32, 24), 256, 0, stream>>>(xb, Wt, Qb, Kf, Vf);
  flash_attn<<<1024, 256, 0, stream>>>(Qb, Kf, Vf, Ctx);
  gemm_out<<<dim3(32, 8), 256, 0, stream>>>(Ctx, Wot, (float*)d_out, bo);
}